// Round 1
// baseline (689.927 us; speedup 1.0000x reference)
//
#include <hip/hip_runtime.h>
#include <hip/hip_bf16.h>

// BahdanauAttention: B=32, S=2048, H=1024, U=1024
//   q2 = query@W2 + b2                                  [B,U]
//   score[b,s] = sum_u tanh(values[b,s]@W1[:,u] + b1[u] + q2[b,u]) * V[u]  (+bv, softmax-invariant)
//   attn = softmax_s(score); context = sum_s attn * values
// Outputs concat: context [B,H]=32768 f32, attn [B,S,1]=65536 f32.
//
// ws layout: values_bf16 [M,H] 128MB | W1T bf16 [U,H] 2MB | q2 f32 [B,U] 128KB

#define B_ 32
#define S_ 2048
#define H_ 1024
#define U_ 1024
#define M_ (B_ * S_)   // 65536

typedef __bf16 bf16;
typedef __bf16 bf16x8 __attribute__((ext_vector_type(8)));
typedef __bf16 bf16x4 __attribute__((ext_vector_type(4)));
typedef float  f32x4  __attribute__((ext_vector_type(4)));

__device__ __forceinline__ void gl2lds16(const void* g, void* l) {
    // 16B/lane direct global->LDS; lds ptr must be wave-uniform (lane*16 auto-offset)
    __builtin_amdgcn_global_load_lds(
        (const __attribute__((address_space(1))) void*)g,
        (__attribute__((address_space(3))) void*)l, 16, 0, 0);
}

// ---------------- 1. cast values fp32 -> bf16 (RNE) ----------------
__global__ void cast_values(const float* __restrict__ in, bf16* __restrict__ out) {
    long i = ((long)blockIdx.x * 256 + threadIdx.x) * 8;
    float4 f0 = *reinterpret_cast<const float4*>(in + i);
    float4 f1 = *reinterpret_cast<const float4*>(in + i + 4);
    bf16x8 o;
    o[0] = (bf16)f0.x; o[1] = (bf16)f0.y; o[2] = (bf16)f0.z; o[3] = (bf16)f0.w;
    o[4] = (bf16)f1.x; o[5] = (bf16)f1.y; o[6] = (bf16)f1.z; o[7] = (bf16)f1.w;
    *reinterpret_cast<bf16x8*>(out + i) = o;
}

// ---------------- 2. W1 [H,U] fp32 -> W1T [U,H] bf16 ----------------
__global__ void transpose_w1(const float* __restrict__ W1, bf16* __restrict__ W1T) {
    __shared__ bf16 t[64 * 65];
    int h0 = blockIdx.x * 64, u0 = blockIdx.y * 64;
    int tid = threadIdx.x;
    #pragma unroll
    for (int i = 0; i < 16; ++i) {
        int idx = i * 256 + tid;
        int r = idx >> 6, c = idx & 63;                     // r: h-local, c: u-local
        t[c * 65 + r] = (bf16)W1[(long)(h0 + r) * U_ + u0 + c];
    }
    __syncthreads();
    #pragma unroll
    for (int i = 0; i < 16; ++i) {
        int idx = i * 256 + tid;
        int r = idx >> 6, c = idx & 63;                     // r: u-local, c: h-local
        W1T[(long)(u0 + r) * H_ + h0 + c] = t[r * 65 + c];
    }
}

// ---------------- 3. q2 = query@W2 + b2 ----------------
__global__ void q2_kernel(const float* __restrict__ query, const float* __restrict__ W2,
                          const float* __restrict__ b2, float* __restrict__ q2) {
    __shared__ float qsh[H_];
    int b = blockIdx.y;
    int u = blockIdx.x * 256 + threadIdx.x;
    for (int i = threadIdx.x; i < H_; i += 256) qsh[i] = query[b * H_ + i];
    __syncthreads();
    float acc = b2[u];
    #pragma unroll 8
    for (int h = 0; h < H_; ++h) acc += qsh[h] * W2[(long)h * U_ + u];
    q2[b * U_ + u] = acc;
}

// ---------------- 4. fused GEMM + tanh + dot(V): score accumulation ----------------
// 128x128 tile, BK=32, 4 waves (2x2), 16x16x32 bf16 MFMA, m97-style staging.
__global__ __launch_bounds__(256) void score_gemm(
    const bf16* __restrict__ A,    // values bf16 [M,H]
    const bf16* __restrict__ BT,   // W1T bf16 [U,H]
    const float* __restrict__ b1, const float* __restrict__ q2,
    const float* __restrict__ V, float* __restrict__ score /* [M] pre-zeroed */)
{
    __shared__ __align__(16) bf16 a_sh[128 * 32];
    __shared__ __align__(16) bf16 b_sh[128 * 32];
    const int tid  = threadIdx.x;
    const int lane = tid & 63;
    const int wave = tid >> 6;
    const int wm = wave >> 1, wn = wave & 1;
    const int mt = blockIdx.x >> 3;     // 8 consecutive blocks share A-tile (L2 reuse)
    const int nt = blockIdx.x & 7;
    const long m0 = (long)mt * 128;
    const int  n0 = nt * 128;
    const int lrow = lane & 15;
    const int quad = lane >> 4;

    f32x4 acc[4][4];
    const f32x4 zero = {0.f, 0.f, 0.f, 0.f};
    #pragma unroll
    for (int mi = 0; mi < 4; ++mi)
        #pragma unroll
        for (int ni = 0; ni < 4; ++ni) acc[mi][ni] = zero;

    const bf16* Abase = A + m0 * H_;
    const bf16* Bbase = BT + (long)n0 * H_;

    for (int kt = 0; kt < H_; kt += 32) {
        // stage A tile [128 rows x 32 k] and B tile [128 n x 32 k]; 8KB each
        #pragma unroll
        for (int i = 0; i < 2; ++i) {
            int q = wave + i * 4;            // 8 chunk-groups of 1KB
            int c = (q << 6) + lane;         // chunk id 0..511
            int row = c >> 2, kp = c & 3;
            gl2lds16(Abase + (long)row * H_ + kt + kp * 8, (void*)(a_sh + (q << 9)));
            gl2lds16(Bbase + (long)row * H_ + kt + kp * 8, (void*)(b_sh + (q << 9)));
        }
        __syncthreads();

        bf16x8 af[4], bg[4];
        #pragma unroll
        for (int mi = 0; mi < 4; ++mi)
            af[mi] = *reinterpret_cast<const bf16x8*>(
                a_sh + ((wm * 64 + mi * 16 + lrow) * 32 + quad * 8));
        #pragma unroll
        for (int ni = 0; ni < 4; ++ni)
            bg[ni] = *reinterpret_cast<const bf16x8*>(
                b_sh + ((wn * 64 + ni * 16 + lrow) * 32 + quad * 8));

        #pragma unroll
        for (int mi = 0; mi < 4; ++mi)
            #pragma unroll
            for (int ni = 0; ni < 4; ++ni)
                acc[mi][ni] = __builtin_amdgcn_mfma_f32_16x16x32_bf16(
                    af[mi], bg[ni], acc[mi][ni], 0, 0, 0);
        __syncthreads();
    }

    // epilogue: tanh(acc + b1 + q2) * V, reduce over u, atomic into score
    const int bb = (int)(m0 / S_);          // tile never straddles batches (128 | 2048)
    float bq[4], vv[4];
    #pragma unroll
    for (int ni = 0; ni < 4; ++ni) {
        int u = n0 + wn * 64 + ni * 16 + lrow;
        bq[ni] = b1[u] + q2[bb * U_ + u];
        vv[ni] = V[u];
    }
    #pragma unroll
    for (int mi = 0; mi < 4; ++mi) {
        #pragma unroll
        for (int r = 0; r < 4; ++r) {
            float s = 0.f;
            #pragma unroll
            for (int ni = 0; ni < 4; ++ni) {
                float x = acc[mi][ni][r] + bq[ni];
                float t = 1.f - 2.f / (__expf(2.f * x) + 1.f);   // tanh
                s += t * vv[ni];
            }
            // reduce across the 16 lanes sharing this row (bits 0-3 of lane)
            s += __shfl_xor(s, 1); s += __shfl_xor(s, 2);
            s += __shfl_xor(s, 4); s += __shfl_xor(s, 8);
            if (lrow == 0)
                atomicAdd(score + m0 + wm * 64 + mi * 16 + quad * 4 + r, s);
        }
    }
}

// ---------------- 5. softmax over s, in place ----------------
__global__ void softmax_kernel(float* __restrict__ attn) {
    __shared__ float sh[S_];
    __shared__ float red[8];
    int b = blockIdx.x, tid = threadIdx.x;
    float* row = attn + (long)b * S_;
    float lmax = -1e30f;
    for (int i = tid; i < S_; i += 256) { float v = row[i]; sh[i] = v; lmax = fmaxf(lmax, v); }
    #pragma unroll
    for (int m = 32; m; m >>= 1) lmax = fmaxf(lmax, __shfl_xor(lmax, m));
    if ((tid & 63) == 0) red[tid >> 6] = lmax;
    __syncthreads();
    float gmax = fmaxf(fmaxf(red[0], red[1]), fmaxf(red[2], red[3]));
    float lsum = 0.f;
    for (int i = tid; i < S_; i += 256) { float e = __expf(sh[i] - gmax); sh[i] = e; lsum += e; }
    #pragma unroll
    for (int m = 32; m; m >>= 1) lsum += __shfl_xor(lsum, m);
    if ((tid & 63) == 0) red[4 + (tid >> 6)] = lsum;
    __syncthreads();
    float inv = 1.f / (red[4] + red[5] + red[6] + red[7]);
    for (int i = tid; i < S_; i += 256) row[i] = sh[i] * inv;
}

// ---------------- 6. context = sum_s attn * values ----------------
__global__ void context_kernel(const bf16* __restrict__ vals, const float* __restrict__ attn,
                               float* __restrict__ ctx /* pre-zeroed */) {
    __shared__ float a_sh[128];
    int b = blockIdx.x >> 4;
    int sc = blockIdx.x & 15;        // 16 s-chunks of 128
    int tid = threadIdx.x;
    if (tid < 128) a_sh[tid] = attn[(long)b * S_ + sc * 128 + tid];
    __syncthreads();
    const bf16* base = vals + ((long)b * S_ + sc * 128) * H_ + tid * 4;
    float ax = 0.f, ay = 0.f, az = 0.f, aw = 0.f;
    #pragma unroll 4
    for (int s = 0; s < 128; ++s) {
        float w = a_sh[s];
        bf16x4 v = *reinterpret_cast<const bf16x4*>(base + (long)s * H_);
        ax += w * (float)v[0]; ay += w * (float)v[1];
        az += w * (float)v[2]; aw += w * (float)v[3];
    }
    float* c = ctx + (long)b * H_ + tid * 4;
    atomicAdd(c + 0, ax); atomicAdd(c + 1, ay);
    atomicAdd(c + 2, az); atomicAdd(c + 3, aw);
}

extern "C" void kernel_launch(void* const* d_in, const int* in_sizes, int n_in,
                              void* d_out, int out_size, void* d_ws, size_t ws_size,
                              hipStream_t stream) {
    const float* query  = (const float*)d_in[0];
    const float* values = (const float*)d_in[1];
    const float* W1     = (const float*)d_in[2];
    const float* b1     = (const float*)d_in[3];
    const float* W2     = (const float*)d_in[4];
    const float* b2     = (const float*)d_in[5];
    const float* V      = (const float*)d_in[6];
    // d_in[7] = bv: softmax-invariant, context unaffected -> unused

    char* ws = (char*)d_ws;
    bf16*  vals_bf = (bf16*)ws;                                        // 128 MB
    bf16*  w1t     = (bf16*)(ws + (size_t)M_ * H_ * 2);                // 2 MB
    float* q2      = (float*)(ws + (size_t)M_ * H_ * 2 + (size_t)U_ * H_ * 2); // 128 KB

    float* ctx  = (float*)d_out;            // [B,H]
    float* attn = (float*)d_out + B_ * H_;  // [B,S]: scores accumulate here, softmax in place

    hipMemsetAsync(d_out, 0, (size_t)(B_ * H_ + B_ * S_) * sizeof(float), stream);

    cast_values  <<<(M_ * H_) / (256 * 8), 256, 0, stream>>>(values, vals_bf);
    transpose_w1 <<<dim3(16, 16),          256, 0, stream>>>(W1, w1t);
    q2_kernel    <<<dim3(U_ / 256, B_),    256, 0, stream>>>(query, W2, b2, q2);
    score_gemm   <<<(M_ / 128) * 8,        256, 0, stream>>>(vals_bf, w1t, b1, q2, V, attn);
    softmax_kernel<<<B_,                   256, 0, stream>>>(attn);
    context_kernel<<<B_ * 16,              256, 0, stream>>>(vals_bf, attn, ctx);
}

// Round 2
// 641.523 us; speedup vs baseline: 1.0755x; 1.0755x over previous
//
#include <hip/hip_runtime.h>
#include <hip/hip_bf16.h>

// BahdanauAttention: B=32, S=2048, H=1024, U=1024
//   q2 = query@W2 + b2                                  [B,U]
//   score[b,s] = sum_u tanh(values[b,s]@W1[:,u] + b1[u] + q2[b,u]) * V[u]  (+bv, softmax-invariant)
//   attn = softmax_s(score); context = sum_s attn * values
// Outputs concat: context [B,H]=32768 f32, attn [B,S,1]=65536 f32.
//
// ws layout: values_bf16 [M,H] 128MB | W1T bf16 [U,H] 2MB | q2 f32 [B,U] 128KB

#define B_ 32
#define S_ 2048
#define H_ 1024
#define U_ 1024
#define M_ (B_ * S_)   // 65536

typedef __bf16 bf16;
typedef __bf16 bf16x8 __attribute__((ext_vector_type(8)));
typedef __bf16 bf16x4 __attribute__((ext_vector_type(4)));
typedef float  f32x4  __attribute__((ext_vector_type(4)));

__device__ __forceinline__ void gl2lds16(const void* g, void* l) {
    // 16B/lane direct global->LDS; lds ptr must be wave-uniform (lane*16 auto-offset)
    __builtin_amdgcn_global_load_lds(
        (const __attribute__((address_space(1))) void*)g,
        (__attribute__((address_space(3))) void*)l, 16, 0, 0);
}

// ---------------- 1. cast values fp32 -> bf16 (RNE) ----------------
__global__ void cast_values(const float* __restrict__ in, bf16* __restrict__ out) {
    long i = ((long)blockIdx.x * 256 + threadIdx.x) * 8;
    float4 f0 = *reinterpret_cast<const float4*>(in + i);
    float4 f1 = *reinterpret_cast<const float4*>(in + i + 4);
    bf16x8 o;
    o[0] = (bf16)f0.x; o[1] = (bf16)f0.y; o[2] = (bf16)f0.z; o[3] = (bf16)f0.w;
    o[4] = (bf16)f1.x; o[5] = (bf16)f1.y; o[6] = (bf16)f1.z; o[7] = (bf16)f1.w;
    *reinterpret_cast<bf16x8*>(out + i) = o;
}

// ---------------- 2. W1 [H,U] fp32 -> W1T [U,H] bf16 ----------------
__global__ void transpose_w1(const float* __restrict__ W1, bf16* __restrict__ W1T) {
    __shared__ bf16 t[64 * 65];
    int h0 = blockIdx.x * 64, u0 = blockIdx.y * 64;
    int tid = threadIdx.x;
    #pragma unroll
    for (int i = 0; i < 16; ++i) {
        int idx = i * 256 + tid;
        int r = idx >> 6, c = idx & 63;                     // r: h-local, c: u-local
        t[c * 65 + r] = (bf16)W1[(long)(h0 + r) * U_ + u0 + c];
    }
    __syncthreads();
    #pragma unroll
    for (int i = 0; i < 16; ++i) {
        int idx = i * 256 + tid;
        int r = idx >> 6, c = idx & 63;                     // r: u-local, c: h-local
        W1T[(long)(u0 + r) * H_ + h0 + c] = t[r * 65 + c];
    }
}

// ---------------- 3. q2 = query@W2 + b2 ----------------
// 512 blocks: (U/64, B); block = 4 k-chunks x 64 u-lanes. K split for latency hiding.
__global__ void q2_kernel(const float* __restrict__ query, const float* __restrict__ W2,
                          const float* __restrict__ b2, float* __restrict__ q2) {
    __shared__ float qsh[H_];
    __shared__ float part[4][64];
    int b = blockIdx.y;
    int u0 = blockIdx.x * 64;
    int tid = threadIdx.x;
    int ul = tid & 63, kc = tid >> 6;
    for (int i = tid; i < H_; i += 256) qsh[i] = query[b * H_ + i];
    __syncthreads();
    float acc = 0.f;
    const float* wp = W2 + (long)(kc * 256) * U_ + u0 + ul;
    #pragma unroll 8
    for (int h = 0; h < 256; ++h) acc += qsh[kc * 256 + h] * wp[(long)h * U_];
    part[kc][ul] = acc;
    __syncthreads();
    if (tid < 64)
        q2[b * U_ + u0 + tid] = part[0][tid] + part[1][tid] + part[2][tid] + part[3][tid]
                                + b2[u0 + tid];
}

// ---------------- 4. fused GEMM + tanh + dot(V): score accumulation ----------------
// 128x128 tile, BK=32, 4 waves (2x2), 16x16x32 bf16 MFMA, m97-style staging.
// XCD swizzle: blocks sharing an A-tile (same mt) share blockIdx%8 -> same XCD L2.
__global__ __launch_bounds__(256) void score_gemm(
    const bf16* __restrict__ A,    // values bf16 [M,H]
    const bf16* __restrict__ BT,   // W1T bf16 [U,H]
    const float* __restrict__ b1, const float* __restrict__ q2,
    const float* __restrict__ V, float* __restrict__ score /* [M] pre-zeroed */)
{
    __shared__ __align__(16) bf16 a_sh[128 * 32];
    __shared__ __align__(16) bf16 b_sh[128 * 32];
    const int tid  = threadIdx.x;
    const int lane = tid & 63;
    const int wave = tid >> 6;
    const int wm = wave >> 1, wn = wave & 1;
    // XCD-aware swizzle: xcd = blk&7 (round-robin dispatch); 8 nt-blocks of one
    // m-tile all carry the same blk%8 so the A-tile is fetched once per XCD.
    const int xcd = blockIdx.x & 7;
    const int i_  = blockIdx.x >> 3;          // 0..511
    const int nt  = i_ & 7;
    const int mt  = xcd * 64 + (i_ >> 3);     // 0..511
    const long m0 = (long)mt * 128;
    const int  n0 = nt * 128;
    const int lrow = lane & 15;
    const int quad = lane >> 4;

    f32x4 acc[4][4];
    const f32x4 zero = {0.f, 0.f, 0.f, 0.f};
    #pragma unroll
    for (int mi = 0; mi < 4; ++mi)
        #pragma unroll
        for (int ni = 0; ni < 4; ++ni) acc[mi][ni] = zero;

    const bf16* Abase = A + m0 * H_;
    const bf16* Bbase = BT + (long)n0 * H_;

    for (int kt = 0; kt < H_; kt += 32) {
        // stage A tile [128 rows x 32 k] and B tile [128 n x 32 k]; 8KB each
        #pragma unroll
        for (int i = 0; i < 2; ++i) {
            int q = wave + i * 4;            // 8 chunk-groups of 1KB
            int c = (q << 6) + lane;         // chunk id 0..511
            int row = c >> 2, kp = c & 3;
            gl2lds16(Abase + (long)row * H_ + kt + kp * 8, (void*)(a_sh + (q << 9)));
            gl2lds16(Bbase + (long)row * H_ + kt + kp * 8, (void*)(b_sh + (q << 9)));
        }
        __syncthreads();

        bf16x8 af[4], bg[4];
        #pragma unroll
        for (int mi = 0; mi < 4; ++mi)
            af[mi] = *reinterpret_cast<const bf16x8*>(
                a_sh + ((wm * 64 + mi * 16 + lrow) * 32 + quad * 8));
        #pragma unroll
        for (int ni = 0; ni < 4; ++ni)
            bg[ni] = *reinterpret_cast<const bf16x8*>(
                b_sh + ((wn * 64 + ni * 16 + lrow) * 32 + quad * 8));

        #pragma unroll
        for (int mi = 0; mi < 4; ++mi)
            #pragma unroll
            for (int ni = 0; ni < 4; ++ni)
                acc[mi][ni] = __builtin_amdgcn_mfma_f32_16x16x32_bf16(
                    af[mi], bg[ni], acc[mi][ni], 0, 0, 0);
        __syncthreads();
    }

    // epilogue: tanh(acc + b1 + q2) * V, reduce over u, atomic into score
    const int bb = (int)(m0 / S_);          // tile never straddles batches (128 | 2048)
    float bq[4], vv[4];
    #pragma unroll
    for (int ni = 0; ni < 4; ++ni) {
        int u = n0 + wn * 64 + ni * 16 + lrow;
        bq[ni] = b1[u] + q2[bb * U_ + u];
        vv[ni] = V[u];
    }
    #pragma unroll
    for (int mi = 0; mi < 4; ++mi) {
        #pragma unroll
        for (int r = 0; r < 4; ++r) {
            float s = 0.f;
            #pragma unroll
            for (int ni = 0; ni < 4; ++ni) {
                float x = acc[mi][ni][r] + bq[ni];
                float t = 1.f - 2.f / (__expf(2.f * x) + 1.f);   // tanh
                s += t * vv[ni];
            }
            // reduce across the 16 lanes sharing this row (bits 0-3 of lane)
            s += __shfl_xor(s, 1); s += __shfl_xor(s, 2);
            s += __shfl_xor(s, 4); s += __shfl_xor(s, 8);
            if (lrow == 0)
                atomicAdd(score + m0 + wm * 64 + mi * 16 + quad * 4 + r, s);
        }
    }
}

// ---------------- 5. softmax over s, in place ----------------
__global__ void softmax_kernel(float* __restrict__ attn) {
    __shared__ float sh[S_];
    __shared__ float red[8];
    int b = blockIdx.x, tid = threadIdx.x;
    float* row = attn + (long)b * S_;
    float lmax = -1e30f;
    for (int i = tid; i < S_; i += 256) { float v = row[i]; sh[i] = v; lmax = fmaxf(lmax, v); }
    #pragma unroll
    for (int m = 32; m; m >>= 1) lmax = fmaxf(lmax, __shfl_xor(lmax, m));
    if ((tid & 63) == 0) red[tid >> 6] = lmax;
    __syncthreads();
    float gmax = fmaxf(fmaxf(red[0], red[1]), fmaxf(red[2], red[3]));
    float lsum = 0.f;
    for (int i = tid; i < S_; i += 256) { float e = __expf(sh[i] - gmax); sh[i] = e; lsum += e; }
    #pragma unroll
    for (int m = 32; m; m >>= 1) lsum += __shfl_xor(lsum, m);
    if ((tid & 63) == 0) red[4 + (tid >> 6)] = lsum;
    __syncthreads();
    float inv = 1.f / (red[4] + red[5] + red[6] + red[7]);
    for (int i = tid; i < S_; i += 256) row[i] = sh[i] * inv;
}

// ---------------- 6. context = sum_s attn * values ----------------
__global__ void context_kernel(const bf16* __restrict__ vals, const float* __restrict__ attn,
                               float* __restrict__ ctx /* pre-zeroed */) {
    __shared__ float a_sh[128];
    int b = blockIdx.x >> 4;
    int sc = blockIdx.x & 15;        // 16 s-chunks of 128
    int tid = threadIdx.x;
    if (tid < 128) a_sh[tid] = attn[(long)b * S_ + sc * 128 + tid];
    __syncthreads();
    const bf16* base = vals + ((long)b * S_ + sc * 128) * H_ + tid * 4;
    float ax = 0.f, ay = 0.f, az = 0.f, aw = 0.f;
    #pragma unroll 4
    for (int s = 0; s < 128; ++s) {
        float w = a_sh[s];
        bf16x4 v = *reinterpret_cast<const bf16x4*>(base + (long)s * H_);
        ax += w * (float)v[0]; ay += w * (float)v[1];
        az += w * (float)v[2]; aw += w * (float)v[3];
    }
    float* c = ctx + (long)b * H_ + tid * 4;
    atomicAdd(c + 0, ax); atomicAdd(c + 1, ay);
    atomicAdd(c + 2, az); atomicAdd(c + 3, aw);
}

extern "C" void kernel_launch(void* const* d_in, const int* in_sizes, int n_in,
                              void* d_out, int out_size, void* d_ws, size_t ws_size,
                              hipStream_t stream) {
    const float* query  = (const float*)d_in[0];
    const float* values = (const float*)d_in[1];
    const float* W1     = (const float*)d_in[2];
    const float* b1     = (const float*)d_in[3];
    const float* W2     = (const float*)d_in[4];
    const float* b2     = (const float*)d_in[5];
    const float* V      = (const float*)d_in[6];
    // d_in[7] = bv: softmax-invariant, context unaffected -> unused

    char* ws = (char*)d_ws;
    bf16*  vals_bf = (bf16*)ws;                                        // 128 MB
    bf16*  w1t     = (bf16*)(ws + (size_t)M_ * H_ * 2);                // 2 MB
    float* q2      = (float*)(ws + (size_t)M_ * H_ * 2 + (size_t)U_ * H_ * 2); // 128 KB

    float* ctx  = (float*)d_out;            // [B,H]
    float* attn = (float*)d_out + B_ * H_;  // [B,S]: scores accumulate here, softmax in place

    hipMemsetAsync(d_out, 0, (size_t)(B_ * H_ + B_ * S_) * sizeof(float), stream);

    cast_values  <<<(M_ * H_) / (256 * 8), 256, 0, stream>>>(values, vals_bf);
    transpose_w1 <<<dim3(16, 16),          256, 0, stream>>>(W1, w1t);
    q2_kernel    <<<dim3(U_ / 64, B_),     256, 0, stream>>>(query, W2, b2, q2);
    score_gemm   <<<(M_ / 128) * 8,        256, 0, stream>>>(vals_bf, w1t, b1, q2, V, attn);
    softmax_kernel<<<B_,                   256, 0, stream>>>(attn);
    context_kernel<<<B_ * 16,              256, 0, stream>>>(vals_bf, attn, ctx);
}

// Round 3
// 616.018 us; speedup vs baseline: 1.1200x; 1.0414x over previous
//
#include <hip/hip_runtime.h>
#include <hip/hip_bf16.h>

// BahdanauAttention: B=32, S=2048, H=1024, U=1024
//   q2 = query@W2 + b2                                  [B,U]
//   score[b,s] = sum_u tanh(values[b,s]@W1[:,u] + b1[u] + q2[b,u]) * V[u]  (+bv, softmax-invariant)
//   attn = softmax_s(score); context = sum_s attn * values
// Outputs concat: context [B,H]=32768 f32, attn [B,S,1]=65536 f32.
//
// score_gemm reads values fp32 directly (no pre-cast kernel), converts to bf16
// in-register, and the nt==0 block per m-tile emits the bf16 copy for context.
// ws layout: values_bf16 [M,H] 128MB | W1T bf16 [U,H] 2MB | q2 f32 [B,U] 128KB

#define B_ 32
#define S_ 2048
#define H_ 1024
#define U_ 1024
#define M_ (B_ * S_)   // 65536

typedef __bf16 bf16;
typedef __bf16 bf16x8 __attribute__((ext_vector_type(8)));
typedef __bf16 bf16x4 __attribute__((ext_vector_type(4)));
typedef float  f32x4  __attribute__((ext_vector_type(4)));

__device__ __forceinline__ void gl2lds16(const void* g, void* l) {
    // 16B/lane direct global->LDS; lds ptr wave-uniform, lane*16 auto-offset
    __builtin_amdgcn_global_load_lds(
        (const __attribute__((address_space(1))) void*)g,
        (__attribute__((address_space(3))) void*)l, 16, 0, 0);
}

// ---------------- W1 [H,U] fp32 -> W1T [U,H] bf16 ----------------
__global__ void transpose_w1(const float* __restrict__ W1, bf16* __restrict__ W1T) {
    __shared__ bf16 t[64 * 65];
    int h0 = blockIdx.x * 64, u0 = blockIdx.y * 64;
    int tid = threadIdx.x;
    #pragma unroll
    for (int i = 0; i < 16; ++i) {
        int idx = i * 256 + tid;
        int r = idx >> 6, c = idx & 63;
        t[c * 65 + r] = (bf16)W1[(long)(h0 + r) * U_ + u0 + c];
    }
    __syncthreads();
    #pragma unroll
    for (int i = 0; i < 16; ++i) {
        int idx = i * 256 + tid;
        int r = idx >> 6, c = idx & 63;
        W1T[(long)(u0 + r) * H_ + h0 + c] = t[r * 65 + c];
    }
}

// ---------------- q2 = query@W2 + b2 ----------------
__global__ void q2_kernel(const float* __restrict__ query, const float* __restrict__ W2,
                          const float* __restrict__ b2, float* __restrict__ q2) {
    __shared__ float qsh[H_];
    __shared__ float part[4][64];
    int b = blockIdx.y;
    int u0 = blockIdx.x * 64;
    int tid = threadIdx.x;
    int ul = tid & 63, kc = tid >> 6;
    for (int i = tid; i < H_; i += 256) qsh[i] = query[b * H_ + i];
    __syncthreads();
    float acc = 0.f;
    const float* wp = W2 + (long)(kc * 256) * U_ + u0 + ul;
    #pragma unroll 8
    for (int h = 0; h < 256; ++h) acc += qsh[kc * 256 + h] * wp[(long)h * U_];
    part[kc][ul] = acc;
    __syncthreads();
    if (tid < 64)
        q2[b * U_ + u0 + tid] = part[0][tid] + part[1][tid] + part[2][tid] + part[3][tid]
                                + b2[u0 + tid];
}

// ---------------- fused GEMM + tanh + dot(V) + bf16-copy emit ----------------
// 128x128 tile, BK=64 (two 32-k halves per barrier), 4 waves (2x2), 16x16x32 MFMA.
// A staged as fp32 (16B chunks XOR-swizzled: stored p holds global chunk p^(row&7)),
// B bf16 (stored p holds global chunk p^((row>>1)&3)) -> fragment ds_read_b128 are
// 2-way bank aliased = free. XCD swizzle: same mt -> same blk%8 -> same XCD L2.
__global__ __launch_bounds__(256, 3) void score_gemm(
    const float* __restrict__ A32,  // values fp32 [M,H]
    const bf16* __restrict__ BT,    // W1T bf16 [U,H]
    const float* __restrict__ b1, const float* __restrict__ q2,
    const float* __restrict__ V, float* __restrict__ score /* [M] pre-zeroed */,
    bf16* __restrict__ vals_bf)     // bf16 copy out for context
{
    __shared__ __align__(16) float a_sh[2 * 128 * 32];   // 32 KB, [hs][row][32]
    __shared__ __align__(16) bf16  b_sh[2 * 128 * 32];   // 16 KB, [hs][row][32]
    const int tid  = threadIdx.x;
    const int lane = tid & 63;
    const int wave = tid >> 6;
    const int wm = wave >> 1, wn = wave & 1;
    const int xcd = blockIdx.x & 7;
    const int i_  = blockIdx.x >> 3;          // 0..511
    const int nt  = i_ & 7;
    const int mt  = xcd * 64 + (i_ >> 3);     // 0..511
    const long m0 = (long)mt * 128;
    const int  n0 = nt * 128;
    const int lrow = lane & 15;
    const int quad = lane >> 4;

    f32x4 acc[4][4];
    const f32x4 zero = {0.f, 0.f, 0.f, 0.f};
    #pragma unroll
    for (int mi = 0; mi < 4; ++mi)
        #pragma unroll
        for (int ni = 0; ni < 4; ++ni) acc[mi][ni] = zero;

    const float* Abase = A32 + m0 * H_;
    const bf16*  Bbase = BT + (long)n0 * H_;

    for (int kt = 0; kt < H_; kt += 64) {
        // ---- stage A: 32 groups of 1KB (2 halves x 16), fp32, swizzled ----
        #pragma unroll
        for (int i = 0; i < 8; ++i) {
            int g  = i * 4 + wave;            // 0..31
            int hs = g >> 4, q = g & 15;
            int row = q * 8 + (lane >> 3);    // 0..127
            int gc  = (lane & 7) ^ (row & 7); // global 16B-chunk index
            gl2lds16(Abase + (long)row * H_ + kt + hs * 32 + gc * 4,
                     (void*)(a_sh + hs * 4096 + q * 256));
        }
        // ---- stage B: 16 groups of 1KB (2 halves x 8), bf16, swizzled ----
        #pragma unroll
        for (int i = 0; i < 4; ++i) {
            int g  = i * 4 + wave;            // 0..15
            int hs = g >> 3, q = g & 7;
            int row = q * 16 + (lane >> 2);   // 0..127
            int gc  = (lane & 3) ^ ((row >> 1) & 3);
            gl2lds16(Bbase + (long)row * H_ + kt + hs * 32 + gc * 8,
                     (void*)(b_sh + hs * 4096 + q * 512));
        }
        __syncthreads();

        #pragma unroll
        for (int hs = 0; hs < 2; ++hs) {
            bf16x8 af[4], bg[4];
            #pragma unroll
            for (int mi = 0; mi < 4; ++mi) {
                int r  = wm * 64 + mi * 16 + lrow;
                int p0 = (2 * quad) ^ (r & 7);
                const float4 lo = *reinterpret_cast<const float4*>(
                    a_sh + hs * 4096 + r * 32 + p0 * 4);
                const float4 hi = *reinterpret_cast<const float4*>(
                    a_sh + hs * 4096 + r * 32 + (p0 ^ 1) * 4);
                bf16x8 f;
                f[0] = (bf16)lo.x; f[1] = (bf16)lo.y; f[2] = (bf16)lo.z; f[3] = (bf16)lo.w;
                f[4] = (bf16)hi.x; f[5] = (bf16)hi.y; f[6] = (bf16)hi.z; f[7] = (bf16)hi.w;
                af[mi] = f;
            }
            #pragma unroll
            for (int ni = 0; ni < 4; ++ni) {
                int r = wn * 64 + ni * 16 + lrow;
                int p = quad ^ ((r >> 1) & 3);
                bg[ni] = *reinterpret_cast<const bf16x8*>(
                    b_sh + hs * 4096 + r * 32 + p * 8);
            }
            #pragma unroll
            for (int mi = 0; mi < 4; ++mi)
                #pragma unroll
                for (int ni = 0; ni < 4; ++ni)
                    acc[mi][ni] = __builtin_amdgcn_mfma_f32_16x16x32_bf16(
                        af[mi], bg[ni], acc[mi][ni], 0, 0, 0);
        }

        // ---- nt==0 block emits the bf16 copy of this A-tile for context ----
        if (nt == 0) {
            int row = tid >> 1, seg = tid & 1, s = row & 7;
            #pragma unroll
            for (int hs = 0; hs < 2; ++hs) {
                float4 c[4];
                #pragma unroll
                for (int j = 0; j < 4; ++j)
                    c[j] = *reinterpret_cast<const float4*>(
                        a_sh + hs * 4096 + row * 32 + (((seg * 4 + j) ^ s) * 4));
                bf16x8 o0, o1;
                o0[0] = (bf16)c[0].x; o0[1] = (bf16)c[0].y; o0[2] = (bf16)c[0].z; o0[3] = (bf16)c[0].w;
                o0[4] = (bf16)c[1].x; o0[5] = (bf16)c[1].y; o0[6] = (bf16)c[1].z; o0[7] = (bf16)c[1].w;
                o1[0] = (bf16)c[2].x; o1[1] = (bf16)c[2].y; o1[2] = (bf16)c[2].z; o1[3] = (bf16)c[2].w;
                o1[4] = (bf16)c[3].x; o1[5] = (bf16)c[3].y; o1[6] = (bf16)c[3].z; o1[7] = (bf16)c[3].w;
                bf16* dst = vals_bf + (m0 + row) * H_ + kt + hs * 32 + seg * 16;
                *reinterpret_cast<bf16x8*>(dst)     = o0;
                *reinterpret_cast<bf16x8*>(dst + 8) = o1;
            }
        }
        __syncthreads();
    }

    // epilogue: tanh(acc + b1 + q2) * V, reduce over u, atomic into score
    const int bb = (int)(m0 / S_);          // tile never straddles batches
    float bq[4], vv[4];
    #pragma unroll
    for (int ni = 0; ni < 4; ++ni) {
        int u = n0 + wn * 64 + ni * 16 + lrow;
        bq[ni] = b1[u] + q2[bb * U_ + u];
        vv[ni] = V[u];
    }
    #pragma unroll
    for (int mi = 0; mi < 4; ++mi) {
        #pragma unroll
        for (int r = 0; r < 4; ++r) {
            float s = 0.f;
            #pragma unroll
            for (int ni = 0; ni < 4; ++ni) {
                float x = acc[mi][ni][r] + bq[ni];
                float t = 1.f - 2.f / (__expf(2.f * x) + 1.f);   // tanh
                s += t * vv[ni];
            }
            s += __shfl_xor(s, 1); s += __shfl_xor(s, 2);
            s += __shfl_xor(s, 4); s += __shfl_xor(s, 8);
            if (lrow == 0)
                atomicAdd(score + m0 + wm * 64 + mi * 16 + quad * 4 + r, s);
        }
    }
}

// ---------------- softmax over s, in place ----------------
__global__ void softmax_kernel(float* __restrict__ attn) {
    __shared__ float sh[S_];
    __shared__ float red[8];
    int b = blockIdx.x, tid = threadIdx.x;
    float* row = attn + (long)b * S_;
    float lmax = -1e30f;
    for (int i = tid; i < S_; i += 256) { float v = row[i]; sh[i] = v; lmax = fmaxf(lmax, v); }
    #pragma unroll
    for (int m = 32; m; m >>= 1) lmax = fmaxf(lmax, __shfl_xor(lmax, m));
    if ((tid & 63) == 0) red[tid >> 6] = lmax;
    __syncthreads();
    float gmax = fmaxf(fmaxf(red[0], red[1]), fmaxf(red[2], red[3]));
    float lsum = 0.f;
    for (int i = tid; i < S_; i += 256) { float e = __expf(sh[i] - gmax); sh[i] = e; lsum += e; }
    #pragma unroll
    for (int m = 32; m; m >>= 1) lsum += __shfl_xor(lsum, m);
    if ((tid & 63) == 0) red[4 + (tid >> 6)] = lsum;
    __syncthreads();
    float inv = 1.f / (red[4] + red[5] + red[6] + red[7]);
    for (int i = tid; i < S_; i += 256) row[i] = sh[i] * inv;
}

// ---------------- context = sum_s attn * values ----------------
__global__ void context_kernel(const bf16* __restrict__ vals, const float* __restrict__ attn,
                               float* __restrict__ ctx /* pre-zeroed */) {
    __shared__ float a_sh[128];
    int b = blockIdx.x >> 4;
    int sc = blockIdx.x & 15;        // 16 s-chunks of 128
    int tid = threadIdx.x;
    if (tid < 128) a_sh[tid] = attn[(long)b * S_ + sc * 128 + tid];
    __syncthreads();
    const bf16* base = vals + ((long)b * S_ + sc * 128) * H_ + tid * 4;
    float ax = 0.f, ay = 0.f, az = 0.f, aw = 0.f;
    #pragma unroll 4
    for (int s = 0; s < 128; ++s) {
        float w = a_sh[s];
        bf16x4 v = *reinterpret_cast<const bf16x4*>(base + (long)s * H_);
        ax += w * (float)v[0]; ay += w * (float)v[1];
        az += w * (float)v[2]; aw += w * (float)v[3];
    }
    float* c = ctx + (long)b * H_ + tid * 4;
    atomicAdd(c + 0, ax); atomicAdd(c + 1, ay);
    atomicAdd(c + 2, az); atomicAdd(c + 3, aw);
}

extern "C" void kernel_launch(void* const* d_in, const int* in_sizes, int n_in,
                              void* d_out, int out_size, void* d_ws, size_t ws_size,
                              hipStream_t stream) {
    const float* query  = (const float*)d_in[0];
    const float* values = (const float*)d_in[1];
    const float* W1     = (const float*)d_in[2];
    const float* b1     = (const float*)d_in[3];
    const float* W2     = (const float*)d_in[4];
    const float* b2     = (const float*)d_in[5];
    const float* V      = (const float*)d_in[6];
    // d_in[7] = bv: softmax-invariant, context unaffected -> unused

    char* ws = (char*)d_ws;
    bf16*  vals_bf = (bf16*)ws;                                        // 128 MB
    bf16*  w1t     = (bf16*)(ws + (size_t)M_ * H_ * 2);                // 2 MB
    float* q2      = (float*)(ws + (size_t)M_ * H_ * 2 + (size_t)U_ * H_ * 2); // 128 KB

    float* ctx  = (float*)d_out;            // [B,H]
    float* attn = (float*)d_out + B_ * H_;  // [B,S]

    hipMemsetAsync(d_out, 0, (size_t)(B_ * H_ + B_ * S_) * sizeof(float), stream);

    transpose_w1  <<<dim3(16, 16),       256, 0, stream>>>(W1, w1t);
    q2_kernel     <<<dim3(U_ / 64, B_),  256, 0, stream>>>(query, W2, b2, q2);
    score_gemm    <<<(M_ / 128) * 8,     256, 0, stream>>>(values, w1t, b1, q2, V, attn, vals_bf);
    softmax_kernel<<<B_,                 256, 0, stream>>>(attn);
    context_kernel<<<B_ * 16,            256, 0, stream>>>(vals_bf, attn, ctx);
}